// Round 6
// baseline (336.410 us; speedup 1.0000x reference)
//
#include <hip/hip_runtime.h>
#include <string.h>

// Problem constants
constexpr int Bc   = 4;
constexpr int Nc   = 16384;
constexpr int Ec   = 131072;   // 2^17
constexpr int Hc   = 8;
constexpr int Dc   = 16;
constexpr int HIDc = 128;
constexpr int BN   = Bc * Nc;  // 65536

// R5 post-mortem: k_attn 53us (VALUBusy 55%, hbm 31%); GEMMs ~200us over 6
// dispatches. R6: (1) fused QKV — A-fragments in registers once, three
// weights staged through one 32KB LDS buffer (h read 96->32MB, 3 launches
// ->1); (2) k_attn edge unroll 4->8 (mean degree 8) for deeper MLP.

typedef __bf16 bf16_t;
typedef bf16_t bf16x8 __attribute__((ext_vector_type(8)));
typedef float  f32x4  __attribute__((ext_vector_type(4)));

union BF8 { bf16x8 v; uint4 u; unsigned short s[8]; };

// ---------- helpers ----------
__device__ inline float b2f(unsigned short u) {
    return __uint_as_float(((unsigned)u) << 16);
}
__device__ inline unsigned short f2b(float f) {
    unsigned b = __float_as_uint(f);
    unsigned r = (b + 0x7FFFu + ((b >> 16) & 1u)) >> 16;  // RNE
    return (unsigned short)r;
}
__device__ inline float lo16(unsigned u) { return __uint_as_float(u << 16); }
__device__ inline float hi16(unsigned u) { return __uint_as_float(u & 0xFFFF0000u); }

// stage 128x128 f32 weight -> LDS bf16, transposed+swizzled:
// wt[n][(c^(n&7))*8 + j] = W[c*8+j][n]
__device__ inline void stage_wt(unsigned short* __restrict__ wt,
                                const float* __restrict__ W, int wPitch, int wcol0,
                                int chunks) {
    for (int idx = threadIdx.x; idx < 128 * chunks; idx += 256) {
        int n = idx & 127;
        int c = idx >> 7;
        BF8 pk;
#pragma unroll
        for (int j = 0; j < 8; ++j)
            pk.v[j] = (bf16_t)W[(size_t)(c * 8 + j) * wPitch + wcol0 + n];
        *(uint4*)&wt[n * (chunks * 8) + (c ^ (n & 7)) * 8] = pk.u;
    }
}

// ---------- fused QKV: A-fragments in regs, 3 weights through one LDS ----------
__global__ __launch_bounds__(256) void k_qkv3(const float* __restrict__ h,
                                              const float* __restrict__ Wq,
                                              const float* __restrict__ Wk,
                                              const float* __restrict__ Wv,
                                              unsigned short* __restrict__ Q,
                                              unsigned short* __restrict__ K,
                                              unsigned short* __restrict__ V) {
    __shared__ unsigned short wt[16384];      // 32 KB, reused for Wq/Wk/Wv
    const int wave = threadIdx.x >> 6, lane = threadIdx.x & 63;
    const int nn = lane & 15, q = lane >> 4;

    // ---- A fragments for both m-iters, loaded once (f32 -> bf16) ----
    bf16x8 afrag[2][4];
#pragma unroll
    for (int it = 0; it < 2; ++it) {
        const int arow = (blockIdx.x * 2 + it) * 64 + wave * 16 + nn;
        const float* A = h + (size_t)arow * 128;
#pragma unroll
        for (int ks = 0; ks < 4; ++ks) {
            int k0 = ks * 32 + q * 8;
            float4 f0 = *(const float4*)(A + k0);
            float4 f1 = *(const float4*)(A + k0 + 4);
            BF8 pk;
            pk.v[0] = (bf16_t)f0.x; pk.v[1] = (bf16_t)f0.y;
            pk.v[2] = (bf16_t)f0.z; pk.v[3] = (bf16_t)f0.w;
            pk.v[4] = (bf16_t)f1.x; pk.v[5] = (bf16_t)f1.y;
            pk.v[6] = (bf16_t)f1.z; pk.v[7] = (bf16_t)f1.w;
            afrag[it][ks] = pk.v;
        }
    }

#pragma unroll 1
    for (int s = 0; s < 3; ++s) {
        const float* W = (s == 0) ? Wq : ((s == 1) ? Wk : Wv);
        unsigned short* O = (s == 0) ? Q : ((s == 1) ? K : V);
        if (s) __syncthreads();               // prior MFMA ds_reads done
        stage_wt(wt, W, 128, 0, 16);
        __syncthreads();
#pragma unroll 1
        for (int it = 0; it < 2; ++it) {
            const int row0 = (blockIdx.x * 2 + it) * 64 + wave * 16;
            f32x4 acc[8];
#pragma unroll
            for (int nt = 0; nt < 8; ++nt) acc[nt] = (f32x4){0.f, 0.f, 0.f, 0.f};
#pragma unroll
            for (int nt = 0; nt < 8; ++nt) {
                int n = nt * 16 + nn;
#pragma unroll
                for (int ks = 0; ks < 4; ++ks) {
                    int c = ks * 4 + q;
                    BF8 bf;
                    bf.u = *(const uint4*)&wt[n * 128 + (c ^ (n & 7)) * 8];
                    acc[nt] = __builtin_amdgcn_mfma_f32_16x16x32_bf16(
                        afrag[it][ks], bf.v, acc[nt], 0, 0, 0);
                }
            }
#pragma unroll
            for (int nt = 0; nt < 8; ++nt) {
                int col = nt * 16 + nn;
#pragma unroll
                for (int r = 0; r < 4; ++r)
                    O[(size_t)(row0 + q * 4 + r) * 128 + col] = f2b(acc[nt][r]);
            }
        }
    }
}

// ---------- unified MFMA GEMM (Wo / ff1 / ff2) ----------
// KD: inner dim (128/256). AF32: A f32 (else bf16). ITERS: 64-row m-iters.
// EPI: 1 bias+relu bf16; 2 bias+resid(f32)+LN bf16; 3 bias+resid(bf16)+LN f32.
template<int KD, bool AF32, int EPI, int ITERS>
__global__ __launch_bounds__(256) void k_gemm(const void* __restrict__ Ap,
                                              const float* __restrict__ W, int wPitch,
                                              const float* __restrict__ bias,
                                              const void* __restrict__ resid,
                                              const float* __restrict__ g,
                                              const float* __restrict__ bb,
                                              void* __restrict__ Out, int oPitch) {
    constexpr int CHUNKS = KD / 8;
    constexpr int KS     = KD / 32;
    __shared__ unsigned short wt[128 * KD];

    stage_wt(wt, W, wPitch, blockIdx.y * 128, CHUNKS);
    __syncthreads();

    const int wave = threadIdx.x >> 6, lane = threadIdx.x & 63;
    const int nn = lane & 15, q = lane >> 4;

#pragma unroll 1
    for (int it = 0; it < ITERS; ++it) {
        const int row0 = (blockIdx.x * ITERS + it) * 64 + wave * 16;
        const int arow = row0 + nn;

        bf16x8 afrag[KS];
        if constexpr (AF32) {
            const float* A = (const float*)Ap + (size_t)arow * KD;
#pragma unroll
            for (int ks = 0; ks < KS; ++ks) {
                int k0 = ks * 32 + q * 8;
                float4 f0 = *(const float4*)(A + k0);
                float4 f1 = *(const float4*)(A + k0 + 4);
                BF8 pk;
                pk.v[0] = (bf16_t)f0.x; pk.v[1] = (bf16_t)f0.y;
                pk.v[2] = (bf16_t)f0.z; pk.v[3] = (bf16_t)f0.w;
                pk.v[4] = (bf16_t)f1.x; pk.v[5] = (bf16_t)f1.y;
                pk.v[6] = (bf16_t)f1.z; pk.v[7] = (bf16_t)f1.w;
                afrag[ks] = pk.v;
            }
        } else {
            const unsigned short* A = (const unsigned short*)Ap + (size_t)arow * KD;
#pragma unroll
            for (int ks = 0; ks < KS; ++ks) {
                BF8 pk;
                pk.u = *(const uint4*)(A + ks * 32 + q * 8);
                afrag[ks] = pk.v;
            }
        }

        f32x4 acc[8];
#pragma unroll
        for (int nt = 0; nt < 8; ++nt) acc[nt] = (f32x4){0.f, 0.f, 0.f, 0.f};
#pragma unroll
        for (int nt = 0; nt < 8; ++nt) {
            int n = nt * 16 + nn;
#pragma unroll
            for (int ks = 0; ks < KS; ++ks) {
                int c = ks * 4 + q;
                BF8 bf;
                bf.u = *(const uint4*)&wt[n * KD + (c ^ (n & 7)) * 8];
                acc[nt] = __builtin_amdgcn_mfma_f32_16x16x32_bf16(afrag[ks], bf.v,
                                                                  acc[nt], 0, 0, 0);
            }
        }

        if constexpr (EPI == 1) {
            unsigned short* O = (unsigned short*)Out;
#pragma unroll
            for (int nt = 0; nt < 8; ++nt) {
                int col = blockIdx.y * 128 + nt * 16 + nn;
                float bv = bias[col];
#pragma unroll
                for (int r = 0; r < 4; ++r)
                    O[(size_t)(row0 + q * 4 + r) * oPitch + col] =
                        f2b(fmaxf(acc[nt][r] + bv, 0.f));
            }
        } else {
            float rs[4] = {0.f, 0.f, 0.f, 0.f}, rq[4] = {0.f, 0.f, 0.f, 0.f};
#pragma unroll
            for (int nt = 0; nt < 8; ++nt) {
                int col = nt * 16 + nn;
                float bv = bias[col];
#pragma unroll
                for (int r = 0; r < 4; ++r) {
                    int row = row0 + q * 4 + r;
                    float res;
                    if constexpr (EPI == 2)
                        res = ((const float*)resid)[(size_t)row * 128 + col];
                    else
                        res = b2f(((const unsigned short*)resid)[(size_t)row * 128 + col]);
                    float x = acc[nt][r] + bv + res;
                    acc[nt][r] = x;
                    rs[r] += x; rq[r] += x * x;
                }
            }
#pragma unroll
            for (int r = 0; r < 4; ++r) {
#pragma unroll
                for (int o = 1; o < 16; o <<= 1) {
                    rs[r] += __shfl_xor(rs[r], o, 64);
                    rq[r] += __shfl_xor(rq[r], o, 64);
                }
            }
            float mean[4], rstd[4];
#pragma unroll
            for (int r = 0; r < 4; ++r) {
                mean[r] = rs[r] * (1.f / 128.f);
                float var = rq[r] * (1.f / 128.f) - mean[r] * mean[r];
                rstd[r] = rsqrtf(var + 1e-5f);
            }
#pragma unroll
            for (int nt = 0; nt < 8; ++nt) {
                int col = nt * 16 + nn;
                float gv = g[col], bv2 = bb[col];
#pragma unroll
                for (int r = 0; r < 4; ++r) {
                    int row = row0 + q * 4 + r;
                    float y = (acc[nt][r] - mean[r]) * rstd[r] * gv + bv2;
                    if constexpr (EPI == 2)
                        ((unsigned short*)Out)[(size_t)row * 128 + col] = f2b(y);
                    else
                        ((float*)Out)[(size_t)row * 128 + col] = y;
                }
            }
        }
    }
}

// ---------- CSR build ----------
__global__ __launch_bounds__(256) void k_init(unsigned* __restrict__ counts) {
    int i = blockIdx.x * 256 + threadIdx.x;
    counts[i] = 0u;
}

__global__ __launch_bounds__(256) void k_hist(const int* __restrict__ eidx,
                                              const int* __restrict__ nedges,
                                              unsigned* __restrict__ counts) {
    int t = blockIdx.x * 256 + threadIdx.x;
    int b = t >> 17;
    int e = t & (Ec - 1);
    if (e >= nedges[b]) return;
    int dst = eidx[(size_t)(b * 2 + 1) * Ec + e];
    atomicAdd(&counts[b * Nc + dst], 1u);
}

__global__ __launch_bounds__(256) void k_scan1(const unsigned* __restrict__ counts,
                                               unsigned* __restrict__ rowptr,
                                               unsigned* __restrict__ bsum) {
    __shared__ unsigned s[256];
    int t = threadIdx.x;
    int i = blockIdx.x * 256 + t;
    unsigned own = counts[i];
    s[t] = own;
    __syncthreads();
#pragma unroll
    for (int off = 1; off < 256; off <<= 1) {
        unsigned v = (t >= off) ? s[t - off] : 0u;
        __syncthreads();
        s[t] += v;
        __syncthreads();
    }
    rowptr[i] = s[t] - own;
    if (t == 255) bsum[blockIdx.x] = s[255];
}

__global__ __launch_bounds__(256) void k_scan2(unsigned* __restrict__ bsum) {
    __shared__ unsigned s[256];
    int t = threadIdx.x;
    unsigned own = bsum[t];
    s[t] = own;
    __syncthreads();
#pragma unroll
    for (int off = 1; off < 256; off <<= 1) {
        unsigned v = (t >= off) ? s[t - off] : 0u;
        __syncthreads();
        s[t] += v;
        __syncthreads();
    }
    bsum[t] = s[t] - own;
}

__global__ __launch_bounds__(256) void k_scan3(unsigned* __restrict__ rowptr,
                                               const unsigned* __restrict__ bsum,
                                               const unsigned* __restrict__ counts,
                                               unsigned* __restrict__ cursor) {
    int i = blockIdx.x * 256 + threadIdx.x;
    unsigned v = rowptr[i] + bsum[blockIdx.x];
    rowptr[i] = v;
    cursor[i] = v;
    if (i == BN - 1) rowptr[BN] = v + counts[i];
}

__global__ __launch_bounds__(256) void k_fill(const int* __restrict__ eidx,
                                              const int* __restrict__ nedges,
                                              unsigned* __restrict__ cursor,
                                              unsigned* __restrict__ csr) {
    int t = blockIdx.x * 256 + threadIdx.x;
    int b = t >> 17;
    int e = t & (Ec - 1);
    if (e >= nedges[b]) return;
    int dst = eidx[(size_t)(b * 2 + 1) * Ec + e];
    unsigned pos = atomicAdd(&cursor[b * Nc + dst], 1u);
    csr[pos] = (unsigned)e;
}

// ---------- attention: wave/node, online softmax, x8-unrolled edge loop ----------
__global__ __launch_bounds__(256) void k_attn(const unsigned short* __restrict__ Q,
                                              const unsigned short* __restrict__ K,
                                              const unsigned short* __restrict__ V,
                                              const float* __restrict__ ef,
                                              const int* __restrict__ eidx,
                                              const unsigned* __restrict__ rowptr,
                                              const unsigned* __restrict__ csr,
                                              const float* __restrict__ We,
                                              unsigned short* __restrict__ attn) {
    int wave = threadIdx.x >> 6, lane = threadIdx.x & 63;
    int i = blockIdx.x * 4 + wave;            // node id in [0, BN)
    int b = i >> 14;                          // N = 16384 = 2^14
    int hh = lane >> 3;                       // head
    int j  = lane & 7;                        // 8 lanes/head, 2 elems each
    int col = hh * 16 + j * 2;

    unsigned qv = *(const unsigned*)(Q + (size_t)i * 128 + col);
    float q0 = lo16(qv), q1 = hi16(qv);
    float we0 = We[hh], we1 = We[8 + hh];

    unsigned p0 = rowptr[i], p1 = rowptr[i + 1];
    const int* srcArr = eidx + (size_t)(b * 2) * Ec;
    const unsigned short* Kb = K + (size_t)b * Nc * 128;
    const unsigned short* Vb = V + (size_t)b * Nc * 128;
    const float* efb = ef + (size_t)b * Ec * 2;

    float m = -INFINITY, l = 0.f, a0 = 0.f, a1 = 0.f;
    unsigned p = p0;
    // ---- batched x8 (mean degree = 8): all loads independent & in flight ----
    for (; p + 8 <= p1; p += 8) {
        unsigned e8[8]; int s8[8]; unsigned kv[8], vv[8]; float2 f8[8];
#pragma unroll
        for (int u = 0; u < 8; ++u) e8[u] = csr[p + u];
#pragma unroll
        for (int u = 0; u < 8; ++u) s8[u] = srcArr[e8[u]];
#pragma unroll
        for (int u = 0; u < 8; ++u) {
            kv[u] = *(const unsigned*)(Kb + (size_t)s8[u] * 128 + col);
            vv[u] = *(const unsigned*)(Vb + (size_t)s8[u] * 128 + col);
            f8[u] = *(const float2*)(efb + (size_t)e8[u] * 2);
        }
        float lg[8];
#pragma unroll
        for (int u = 0; u < 8; ++u) {
            float d = q0 * lo16(kv[u]) + q1 * hi16(kv[u]);
            d += __shfl_xor(d, 1, 64);
            d += __shfl_xor(d, 2, 64);
            d += __shfl_xor(d, 4, 64);
            lg[u] = 0.25f * d + f8[u].x * we0 + f8[u].y * we1;
        }
        float M = m;
#pragma unroll
        for (int u = 0; u < 8; ++u) M = fmaxf(M, lg[u]);
        float sc = __expf(m - M);
        float pr[8];
#pragma unroll
        for (int u = 0; u < 8; ++u) pr[u] = __expf(lg[u] - M);
        float ls = 0.f, s0 = 0.f, s1 = 0.f;
#pragma unroll
        for (int u = 0; u < 8; ++u) {
            ls += pr[u];
            s0 += pr[u] * lo16(vv[u]);
            s1 += pr[u] * hi16(vv[u]);
        }
        l  = l * sc + ls;
        a0 = a0 * sc + s0;
        a1 = a1 * sc + s1;
        m = M;
    }
    // ---- batched x4 ----
    for (; p + 4 <= p1; p += 4) {
        unsigned e4[4]; int s4[4]; unsigned kv[4], vv[4]; float2 f4[4];
#pragma unroll
        for (int u = 0; u < 4; ++u) e4[u] = csr[p + u];
#pragma unroll
        for (int u = 0; u < 4; ++u) s4[u] = srcArr[e4[u]];
#pragma unroll
        for (int u = 0; u < 4; ++u) {
            kv[u] = *(const unsigned*)(Kb + (size_t)s4[u] * 128 + col);
            vv[u] = *(const unsigned*)(Vb + (size_t)s4[u] * 128 + col);
            f4[u] = *(const float2*)(efb + (size_t)e4[u] * 2);
        }
        float lg[4];
#pragma unroll
        for (int u = 0; u < 4; ++u) {
            float d = q0 * lo16(kv[u]) + q1 * hi16(kv[u]);
            d += __shfl_xor(d, 1, 64);
            d += __shfl_xor(d, 2, 64);
            d += __shfl_xor(d, 4, 64);
            lg[u] = 0.25f * d + f4[u].x * we0 + f4[u].y * we1;
        }
        float M = fmaxf(fmaxf(fmaxf(lg[0], lg[1]), fmaxf(lg[2], lg[3])), m);
        float sc = __expf(m - M);
        float pr[4];
#pragma unroll
        for (int u = 0; u < 4; ++u) pr[u] = __expf(lg[u] - M);
        l  = l * sc + ((pr[0] + pr[1]) + (pr[2] + pr[3]));
        a0 = a0 * sc + pr[0] * lo16(vv[0]) + pr[1] * lo16(vv[1])
                     + pr[2] * lo16(vv[2]) + pr[3] * lo16(vv[3]);
        a1 = a1 * sc + pr[0] * hi16(vv[0]) + pr[1] * hi16(vv[1])
                     + pr[2] * hi16(vv[2]) + pr[3] * hi16(vv[3]);
        m = M;
    }
    // ---- remainder ----
    for (; p < p1; ++p) {
        int e = (int)csr[p];
        int src = srcArr[e];
        unsigned kv = *(const unsigned*)(Kb + (size_t)src * 128 + col);
        unsigned vv = *(const unsigned*)(Vb + (size_t)src * 128 + col);
        float2 f2v = *(const float2*)(efb + (size_t)e * 2);
        float d = q0 * lo16(kv) + q1 * hi16(kv);
        d += __shfl_xor(d, 1, 64);
        d += __shfl_xor(d, 2, 64);
        d += __shfl_xor(d, 4, 64);
        float lg = 0.25f * d + f2v.x * we0 + f2v.y * we1;
        float nm = fmaxf(m, lg);
        float sc = __expf(m - nm);
        float pr = __expf(lg - nm);
        l  = l * sc + pr;
        a0 = a0 * sc + pr * lo16(vv);
        a1 = a1 * sc + pr * hi16(vv);
        m = nm;
    }
    float rcp = 1.f / fmaxf(l, 1e-6f);
    unsigned pack = (unsigned)f2b(a0 * rcp) | ((unsigned)f2b(a1 * rcp) << 16);
    *(unsigned*)(attn + (size_t)i * 128 + col) = pack;
}

extern "C" void kernel_launch(void* const* d_in, const int* in_sizes, int n_in,
                              void* d_out, int out_size, void* d_ws, size_t ws_size,
                              hipStream_t stream) {
    const float* h    = (const float*)d_in[0];
    const float* ef   = (const float*)d_in[1];
    const int*   eidx = (const int*)d_in[2];
    const int*   ne   = (const int*)d_in[3];
    const float* Wq   = (const float*)d_in[4];
    const float* Wk   = (const float*)d_in[5];
    const float* Wv   = (const float*)d_in[6];
    const float* Wo   = (const float*)d_in[7];
    const float* bo   = (const float*)d_in[8];
    const float* We   = (const float*)d_in[9];
    const float* ln1g = (const float*)d_in[10];
    const float* ln1b = (const float*)d_in[11];
    const float* ln2g = (const float*)d_in[12];
    const float* ln2b = (const float*)d_in[13];
    const float* ff1  = (const float*)d_in[14];
    const float* b1   = (const float*)d_in[15];
    const float* ff2  = (const float*)d_in[16];
    const float* b2   = (const float*)d_in[17];

    constexpr size_t MB = 1024 * 1024;
    char* ws = (char*)d_ws;
    unsigned short* Q       = (unsigned short*)(ws + 0 * MB);    // 16 MB bf16
    unsigned short* Kp      = (unsigned short*)(ws + 16 * MB);   // 16 MB bf16
    unsigned short* V       = (unsigned short*)(ws + 32 * MB);   // 16 MB bf16
    unsigned short* attn    = (unsigned short*)(ws + 48 * MB);   // 16 MB bf16
    unsigned short* h1      = (unsigned short*)(ws + 64 * MB);   // 16 MB bf16
    unsigned short* mid     = (unsigned short*)(ws + 80 * MB);   // 32 MB bf16
    unsigned*       counts  = (unsigned*)(ws + 112 * MB);        // 256 KB
    unsigned*       rowptr  = (unsigned*)(ws + 113 * MB);        // 256 KB + 4
    unsigned*       cursor  = (unsigned*)(ws + 114 * MB);        // 256 KB
    unsigned*       bsum    = (unsigned*)(ws + 115 * MB);        // 1 KB
    unsigned*       csr     = (unsigned*)(ws + 116 * MB);        // 2 MB

    const int edgeBlocks = (Bc * Ec) / 256;      // 2048
    const int scanBlocks = BN / 256;             // 256
    const int gemmBlocks = BN / 128;             // 512 (2 m-iters of 64 rows)

    // CSR build
    k_init<<<scanBlocks, 256, 0, stream>>>(counts);
    k_hist<<<edgeBlocks, 256, 0, stream>>>(eidx, ne, counts);
    k_scan1<<<scanBlocks, 256, 0, stream>>>(counts, rowptr, bsum);
    k_scan2<<<1, 256, 0, stream>>>(bsum);
    k_scan3<<<scanBlocks, 256, 0, stream>>>(rowptr, bsum, counts, cursor);
    k_fill<<<edgeBlocks, 256, 0, stream>>>(eidx, ne, cursor, csr);

    // Fused QKV (h read once, three weights through one LDS buffer)
    k_qkv3<<<gemmBlocks, 256, 0, stream>>>(h, Wq, Wk, Wv, Q, Kp, V);

    // Attention (bf16 out)
    k_attn<<<BN / 4, 256, 0, stream>>>(Q, Kp, V, ef, eidx, rowptr, csr, We, attn);

    // Wo + bo + residual(h,f32) + LN1 -> h1 (bf16); A = attn (bf16)
    k_gemm<128, false, 2, 2><<<dim3(gemmBlocks, 1), 256, 0, stream>>>(
        attn, Wo, 128, bo, h, ln1g, ln1b, h1, 128);

    // ff1 + b1 + relu -> mid (bf16), two 128-col halves
    k_gemm<128, false, 1, 2><<<dim3(gemmBlocks, 2), 256, 0, stream>>>(
        h1, ff1, 256, b1, nullptr, nullptr, nullptr, mid, 256);

    // ff2 + b2 + residual(h1,bf16) + LN2 -> out (f32)
    k_gemm<256, false, 3, 2><<<dim3(gemmBlocks, 1), 256, 0, stream>>>(
        mid, ff2, 128, b2, h1, ln2g, ln2b, d_out, 128);
}

// Round 7
// 313.424 us; speedup vs baseline: 1.0733x; 1.0733x over previous
//
#include <hip/hip_runtime.h>
#include <string.h>

// Problem constants
constexpr int Bc   = 4;
constexpr int Nc   = 16384;
constexpr int Ec   = 131072;   // 2^17
constexpr int Hc   = 8;
constexpr int Dc   = 16;
constexpr int HIDc = 128;
constexpr int BN   = Bc * Nc;  // 65536

// R6 post-mortem: attn x8 regressed (59 vs 53, revert to x4). GEMM phase
// (~280us) dominated by per-block weight staging: 8 scattered dword loads +
// 8 f32->bf16 converts per 16B of LDS, paid by every block. R7: k_prep
// builds all weight tiles ONCE (transposed+swizzled bf16, exact LDS image);
// GEMM staging becomes a contiguous uint4 copy.

typedef __bf16 bf16_t;
typedef bf16_t bf16x8 __attribute__((ext_vector_type(8)));
typedef float  f32x4  __attribute__((ext_vector_type(4)));

union BF8 { bf16x8 v; uint4 u; unsigned short s[8]; };

// ---------- helpers ----------
__device__ inline float b2f(unsigned short u) {
    return __uint_as_float(((unsigned)u) << 16);
}
__device__ inline unsigned short f2b(float f) {
    unsigned b = __float_as_uint(f);
    unsigned r = (b + 0x7FFFu + ((b >> 16) & 1u)) >> 16;  // RNE
    return (unsigned short)r;
}
__device__ inline float lo16(unsigned u) { return __uint_as_float(u << 16); }
__device__ inline float hi16(unsigned u) { return __uint_as_float(u & 0xFFFF0000u); }

// ---------- weight prep: transposed+swizzled bf16 tiles (exact LDS image) ----
// tile layout: wt[n*KD + (c^(n&7))*8 + j] = W[(c*8+j)*pitch + col0 + n]
// tiles: 0=Wq 1=Wk 2=Wv 3=Wo (KD=128, 16384 shorts each)
//        4=ff1[:,0:128] 5=ff1[:,128:256] (KD=128)
//        6=ff2 (KD=256, 32768 shorts)
__global__ __launch_bounds__(1024) void k_prep(const float* __restrict__ Wq,
                                               const float* __restrict__ Wk,
                                               const float* __restrict__ Wv,
                                               const float* __restrict__ Wo,
                                               const float* __restrict__ ff1,
                                               const float* __restrict__ ff2,
                                               unsigned short* __restrict__ wbuf) {
    int t = blockIdx.x;
    const float* W;
    int pitch, col0, chunks;
    size_t off = (size_t)t * 16384;
    switch (t) {
        case 0: W = Wq;  pitch = 128; col0 = 0;   chunks = 16; break;
        case 1: W = Wk;  pitch = 128; col0 = 0;   chunks = 16; break;
        case 2: W = Wv;  pitch = 128; col0 = 0;   chunks = 16; break;
        case 3: W = Wo;  pitch = 128; col0 = 0;   chunks = 16; break;
        case 4: W = ff1; pitch = 256; col0 = 0;   chunks = 16; break;
        case 5: W = ff1; pitch = 256; col0 = 128; chunks = 16; break;
        default: W = ff2; pitch = 128; col0 = 0;  chunks = 32; break;
    }
    const int KD = chunks * 8;
    for (int idx = threadIdx.x; idx < 128 * chunks; idx += 1024) {
        int n = idx & 127;
        int c = idx >> 7;
        BF8 pk;
#pragma unroll
        for (int j = 0; j < 8; ++j)
            pk.v[j] = (bf16_t)W[(size_t)(c * 8 + j) * pitch + col0 + n];
        *(uint4*)&wbuf[off + (size_t)n * KD + (c ^ (n & 7)) * 8] = pk.u;
    }
}

// ---------- fused QKV: A-fragments in regs, 3 prepped tiles via one LDS ----
__global__ __launch_bounds__(256) void k_qkv3(const float* __restrict__ h,
                                              const unsigned short* __restrict__ wbuf,
                                              unsigned short* __restrict__ Q,
                                              unsigned short* __restrict__ K,
                                              unsigned short* __restrict__ V) {
    __shared__ unsigned short wt[16384];      // 32 KB, reused for Wq/Wk/Wv
    const int wave = threadIdx.x >> 6, lane = threadIdx.x & 63;
    const int nn = lane & 15, q = lane >> 4;

    // ---- A fragments for both m-iters, loaded once (f32 -> bf16) ----
    bf16x8 afrag[2][4];
#pragma unroll
    for (int it = 0; it < 2; ++it) {
        const int arow = (blockIdx.x * 2 + it) * 64 + wave * 16 + nn;
        const float* A = h + (size_t)arow * 128;
#pragma unroll
        for (int ks = 0; ks < 4; ++ks) {
            int k0 = ks * 32 + q * 8;
            float4 f0 = *(const float4*)(A + k0);
            float4 f1 = *(const float4*)(A + k0 + 4);
            BF8 pk;
            pk.v[0] = (bf16_t)f0.x; pk.v[1] = (bf16_t)f0.y;
            pk.v[2] = (bf16_t)f0.z; pk.v[3] = (bf16_t)f0.w;
            pk.v[4] = (bf16_t)f1.x; pk.v[5] = (bf16_t)f1.y;
            pk.v[6] = (bf16_t)f1.z; pk.v[7] = (bf16_t)f1.w;
            afrag[it][ks] = pk.v;
        }
    }

#pragma unroll 1
    for (int s = 0; s < 3; ++s) {
        unsigned short* O = (s == 0) ? Q : ((s == 1) ? K : V);
        if (s) __syncthreads();               // prior MFMA ds_reads done
        {   // contiguous copy of prepped tile s
            const uint4* src = (const uint4*)(wbuf + (size_t)s * 16384);
            uint4* dst = (uint4*)wt;
            for (int i = threadIdx.x; i < 2048; i += 256) dst[i] = src[i];
        }
        __syncthreads();
#pragma unroll 1
        for (int it = 0; it < 2; ++it) {
            const int row0 = (blockIdx.x * 2 + it) * 64 + wave * 16;
            f32x4 acc[8];
#pragma unroll
            for (int nt = 0; nt < 8; ++nt) acc[nt] = (f32x4){0.f, 0.f, 0.f, 0.f};
#pragma unroll
            for (int nt = 0; nt < 8; ++nt) {
                int n = nt * 16 + nn;
#pragma unroll
                for (int ks = 0; ks < 4; ++ks) {
                    int c = ks * 4 + q;
                    BF8 bf;
                    bf.u = *(const uint4*)&wt[n * 128 + (c ^ (n & 7)) * 8];
                    acc[nt] = __builtin_amdgcn_mfma_f32_16x16x32_bf16(
                        afrag[it][ks], bf.v, acc[nt], 0, 0, 0);
                }
            }
#pragma unroll
            for (int nt = 0; nt < 8; ++nt) {
                int col = nt * 16 + nn;
#pragma unroll
                for (int r = 0; r < 4; ++r)
                    O[(size_t)(row0 + q * 4 + r) * 128 + col] = f2b(acc[nt][r]);
            }
        }
    }
}

// ---------- unified MFMA GEMM (Wo / ff1 / ff2), prepped-weight staging ------
// KD: inner dim (128/256). ITERS: 64-row m-iters. EPI: 1 bias+relu bf16;
// 2 bias+resid(f32)+LN bf16; 3 bias+resid(bf16)+LN f32. A is bf16.
template<int KD, int EPI, int ITERS>
__global__ __launch_bounds__(256) void k_gemm(const void* __restrict__ Ap,
                                              const unsigned short* __restrict__ Wt,
                                              const float* __restrict__ bias,
                                              const void* __restrict__ resid,
                                              const float* __restrict__ g,
                                              const float* __restrict__ bb,
                                              void* __restrict__ Out, int oPitch) {
    constexpr int KS = KD / 32;
    __shared__ unsigned short wt[128 * KD];

    {   // contiguous copy of prepped tile (y-half already baked in)
        const uint4* src = (const uint4*)(Wt + (size_t)blockIdx.y * 128 * KD);
        uint4* dst = (uint4*)wt;
        for (int i = threadIdx.x; i < 128 * KD / 8; i += 256) dst[i] = src[i];
    }
    __syncthreads();

    const int wave = threadIdx.x >> 6, lane = threadIdx.x & 63;
    const int nn = lane & 15, q = lane >> 4;

#pragma unroll 1
    for (int it = 0; it < ITERS; ++it) {
        const int row0 = (blockIdx.x * ITERS + it) * 64 + wave * 16;
        const int arow = row0 + nn;

        bf16x8 afrag[KS];
        const unsigned short* A = (const unsigned short*)Ap + (size_t)arow * KD;
#pragma unroll
        for (int ks = 0; ks < KS; ++ks) {
            BF8 pk;
            pk.u = *(const uint4*)(A + ks * 32 + q * 8);
            afrag[ks] = pk.v;
        }

        f32x4 acc[8];
#pragma unroll
        for (int nt = 0; nt < 8; ++nt) acc[nt] = (f32x4){0.f, 0.f, 0.f, 0.f};
#pragma unroll
        for (int nt = 0; nt < 8; ++nt) {
            int n = nt * 16 + nn;
#pragma unroll
            for (int ks = 0; ks < KS; ++ks) {
                int c = ks * 4 + q;
                BF8 bf;
                bf.u = *(const uint4*)&wt[n * KD + (c ^ (n & 7)) * 8];
                acc[nt] = __builtin_amdgcn_mfma_f32_16x16x32_bf16(afrag[ks], bf.v,
                                                                  acc[nt], 0, 0, 0);
            }
        }

        if constexpr (EPI == 1) {
            unsigned short* O = (unsigned short*)Out;
#pragma unroll
            for (int nt = 0; nt < 8; ++nt) {
                int col = blockIdx.y * 128 + nt * 16 + nn;
                float bv = bias[col];
#pragma unroll
                for (int r = 0; r < 4; ++r)
                    O[(size_t)(row0 + q * 4 + r) * oPitch + col] =
                        f2b(fmaxf(acc[nt][r] + bv, 0.f));
            }
        } else {
            float rs[4] = {0.f, 0.f, 0.f, 0.f}, rq[4] = {0.f, 0.f, 0.f, 0.f};
#pragma unroll
            for (int nt = 0; nt < 8; ++nt) {
                int col = nt * 16 + nn;
                float bv = bias[col];
#pragma unroll
                for (int r = 0; r < 4; ++r) {
                    int row = row0 + q * 4 + r;
                    float res;
                    if constexpr (EPI == 2)
                        res = ((const float*)resid)[(size_t)row * 128 + col];
                    else
                        res = b2f(((const unsigned short*)resid)[(size_t)row * 128 + col]);
                    float x = acc[nt][r] + bv + res;
                    acc[nt][r] = x;
                    rs[r] += x; rq[r] += x * x;
                }
            }
#pragma unroll
            for (int r = 0; r < 4; ++r) {
#pragma unroll
                for (int o = 1; o < 16; o <<= 1) {
                    rs[r] += __shfl_xor(rs[r], o, 64);
                    rq[r] += __shfl_xor(rq[r], o, 64);
                }
            }
            float mean[4], rstd[4];
#pragma unroll
            for (int r = 0; r < 4; ++r) {
                mean[r] = rs[r] * (1.f / 128.f);
                float var = rq[r] * (1.f / 128.f) - mean[r] * mean[r];
                rstd[r] = rsqrtf(var + 1e-5f);
            }
#pragma unroll
            for (int nt = 0; nt < 8; ++nt) {
                int col = nt * 16 + nn;
                float gv = g[col], bv2 = bb[col];
#pragma unroll
                for (int r = 0; r < 4; ++r) {
                    int row = row0 + q * 4 + r;
                    float y = (acc[nt][r] - mean[r]) * rstd[r] * gv + bv2;
                    if constexpr (EPI == 2)
                        ((unsigned short*)Out)[(size_t)row * 128 + col] = f2b(y);
                    else
                        ((float*)Out)[(size_t)row * 128 + col] = y;
                }
            }
        }
    }
}

// ---------- CSR build ----------
__global__ __launch_bounds__(256) void k_init(unsigned* __restrict__ counts) {
    int i = blockIdx.x * 256 + threadIdx.x;
    counts[i] = 0u;
}

__global__ __launch_bounds__(256) void k_hist(const int* __restrict__ eidx,
                                              const int* __restrict__ nedges,
                                              unsigned* __restrict__ counts) {
    int t = blockIdx.x * 256 + threadIdx.x;
    int b = t >> 17;
    int e = t & (Ec - 1);
    if (e >= nedges[b]) return;
    int dst = eidx[(size_t)(b * 2 + 1) * Ec + e];
    atomicAdd(&counts[b * Nc + dst], 1u);
}

__global__ __launch_bounds__(256) void k_scan1(const unsigned* __restrict__ counts,
                                               unsigned* __restrict__ rowptr,
                                               unsigned* __restrict__ bsum) {
    __shared__ unsigned s[256];
    int t = threadIdx.x;
    int i = blockIdx.x * 256 + t;
    unsigned own = counts[i];
    s[t] = own;
    __syncthreads();
#pragma unroll
    for (int off = 1; off < 256; off <<= 1) {
        unsigned v = (t >= off) ? s[t - off] : 0u;
        __syncthreads();
        s[t] += v;
        __syncthreads();
    }
    rowptr[i] = s[t] - own;
    if (t == 255) bsum[blockIdx.x] = s[255];
}

__global__ __launch_bounds__(256) void k_scan2(unsigned* __restrict__ bsum) {
    __shared__ unsigned s[256];
    int t = threadIdx.x;
    unsigned own = bsum[t];
    s[t] = own;
    __syncthreads();
#pragma unroll
    for (int off = 1; off < 256; off <<= 1) {
        unsigned v = (t >= off) ? s[t - off] : 0u;
        __syncthreads();
        s[t] += v;
        __syncthreads();
    }
    bsum[t] = s[t] - own;
}

__global__ __launch_bounds__(256) void k_scan3(unsigned* __restrict__ rowptr,
                                               const unsigned* __restrict__ bsum,
                                               const unsigned* __restrict__ counts,
                                               unsigned* __restrict__ cursor) {
    int i = blockIdx.x * 256 + threadIdx.x;
    unsigned v = rowptr[i] + bsum[blockIdx.x];
    rowptr[i] = v;
    cursor[i] = v;
    if (i == BN - 1) rowptr[BN] = v + counts[i];
}

__global__ __launch_bounds__(256) void k_fill(const int* __restrict__ eidx,
                                              const int* __restrict__ nedges,
                                              unsigned* __restrict__ cursor,
                                              unsigned* __restrict__ csr) {
    int t = blockIdx.x * 256 + threadIdx.x;
    int b = t >> 17;
    int e = t & (Ec - 1);
    if (e >= nedges[b]) return;
    int dst = eidx[(size_t)(b * 2 + 1) * Ec + e];
    unsigned pos = atomicAdd(&cursor[b * Nc + dst], 1u);
    csr[pos] = (unsigned)e;
}

// ---------- attention: wave/node, online softmax, x4-unrolled edge loop ----
__global__ __launch_bounds__(256) void k_attn(const unsigned short* __restrict__ Q,
                                              const unsigned short* __restrict__ K,
                                              const unsigned short* __restrict__ V,
                                              const float* __restrict__ ef,
                                              const int* __restrict__ eidx,
                                              const unsigned* __restrict__ rowptr,
                                              const unsigned* __restrict__ csr,
                                              const float* __restrict__ We,
                                              unsigned short* __restrict__ attn) {
    int wave = threadIdx.x >> 6, lane = threadIdx.x & 63;
    int i = blockIdx.x * 4 + wave;            // node id in [0, BN)
    int b = i >> 14;                          // N = 16384 = 2^14
    int hh = lane >> 3;                       // head
    int j  = lane & 7;                        // 8 lanes/head, 2 elems each
    int col = hh * 16 + j * 2;

    unsigned qv = *(const unsigned*)(Q + (size_t)i * 128 + col);
    float q0 = lo16(qv), q1 = hi16(qv);
    float we0 = We[hh], we1 = We[8 + hh];

    unsigned p0 = rowptr[i], p1 = rowptr[i + 1];
    const int* srcArr = eidx + (size_t)(b * 2) * Ec;
    const unsigned short* Kb = K + (size_t)b * Nc * 128;
    const unsigned short* Vb = V + (size_t)b * Nc * 128;
    const float* efb = ef + (size_t)b * Ec * 2;

    float m = -INFINITY, l = 0.f, a0 = 0.f, a1 = 0.f;
    unsigned p = p0;
    // ---- batched x4: all loads independent & in flight before any use ----
    for (; p + 4 <= p1; p += 4) {
        unsigned e4[4]; int s4[4]; unsigned kv[4], vv[4]; float2 f4[4];
#pragma unroll
        for (int u = 0; u < 4; ++u) e4[u] = csr[p + u];
#pragma unroll
        for (int u = 0; u < 4; ++u) s4[u] = srcArr[e4[u]];
#pragma unroll
        for (int u = 0; u < 4; ++u) {
            kv[u] = *(const unsigned*)(Kb + (size_t)s4[u] * 128 + col);
            vv[u] = *(const unsigned*)(Vb + (size_t)s4[u] * 128 + col);
            f4[u] = *(const float2*)(efb + (size_t)e4[u] * 2);
        }
        float lg[4];
#pragma unroll
        for (int u = 0; u < 4; ++u) {
            float d = q0 * lo16(kv[u]) + q1 * hi16(kv[u]);
            d += __shfl_xor(d, 1, 64);
            d += __shfl_xor(d, 2, 64);
            d += __shfl_xor(d, 4, 64);
            lg[u] = 0.25f * d + f4[u].x * we0 + f4[u].y * we1;
        }
        float M = fmaxf(fmaxf(fmaxf(lg[0], lg[1]), fmaxf(lg[2], lg[3])), m);
        float sc = __expf(m - M);
        float pr[4];
#pragma unroll
        for (int u = 0; u < 4; ++u) pr[u] = __expf(lg[u] - M);
        l  = l * sc + ((pr[0] + pr[1]) + (pr[2] + pr[3]));
        a0 = a0 * sc + pr[0] * lo16(vv[0]) + pr[1] * lo16(vv[1])
                     + pr[2] * lo16(vv[2]) + pr[3] * lo16(vv[3]);
        a1 = a1 * sc + pr[0] * hi16(vv[0]) + pr[1] * hi16(vv[1])
                     + pr[2] * hi16(vv[2]) + pr[3] * hi16(vv[3]);
        m = M;
    }
    // ---- remainder ----
    for (; p < p1; ++p) {
        int e = (int)csr[p];
        int src = srcArr[e];
        unsigned kv = *(const unsigned*)(Kb + (size_t)src * 128 + col);
        unsigned vv = *(const unsigned*)(Vb + (size_t)src * 128 + col);
        float2 f2v = *(const float2*)(efb + (size_t)e * 2);
        float d = q0 * lo16(kv) + q1 * hi16(kv);
        d += __shfl_xor(d, 1, 64);
        d += __shfl_xor(d, 2, 64);
        d += __shfl_xor(d, 4, 64);
        float lg = 0.25f * d + f2v.x * we0 + f2v.y * we1;
        float nm = fmaxf(m, lg);
        float sc = __expf(m - nm);
        float pr = __expf(lg - nm);
        l  = l * sc + pr;
        a0 = a0 * sc + pr * lo16(vv);
        a1 = a1 * sc + pr * hi16(vv);
        m = nm;
    }
    float rcp = 1.f / fmaxf(l, 1e-6f);
    unsigned pack = (unsigned)f2b(a0 * rcp) | ((unsigned)f2b(a1 * rcp) << 16);
    *(unsigned*)(attn + (size_t)i * 128 + col) = pack;
}

extern "C" void kernel_launch(void* const* d_in, const int* in_sizes, int n_in,
                              void* d_out, int out_size, void* d_ws, size_t ws_size,
                              hipStream_t stream) {
    const float* h    = (const float*)d_in[0];
    const float* ef   = (const float*)d_in[1];
    const int*   eidx = (const int*)d_in[2];
    const int*   ne   = (const int*)d_in[3];
    const float* Wq   = (const float*)d_in[4];
    const float* Wk   = (const float*)d_in[5];
    const float* Wv   = (const float*)d_in[6];
    const float* Wo   = (const float*)d_in[7];
    const float* bo   = (const float*)d_in[8];
    const float* We   = (const float*)d_in[9];
    const float* ln1g = (const float*)d_in[10];
    const float* ln1b = (const float*)d_in[11];
    const float* ln2g = (const float*)d_in[12];
    const float* ln2b = (const float*)d_in[13];
    const float* ff1  = (const float*)d_in[14];
    const float* b1   = (const float*)d_in[15];
    const float* ff2  = (const float*)d_in[16];
    const float* b2   = (const float*)d_in[17];

    constexpr size_t MB = 1024 * 1024;
    char* ws = (char*)d_ws;
    unsigned short* Q       = (unsigned short*)(ws + 0 * MB);    // 16 MB bf16
    unsigned short* Kp      = (unsigned short*)(ws + 16 * MB);   // 16 MB bf16
    unsigned short* V       = (unsigned short*)(ws + 32 * MB);   // 16 MB bf16
    unsigned short* attn    = (unsigned short*)(ws + 48 * MB);   // 16 MB bf16
    unsigned short* h1      = (unsigned short*)(ws + 64 * MB);   // 16 MB bf16
    unsigned short* mid     = (unsigned short*)(ws + 80 * MB);   // 32 MB bf16
    unsigned*       counts  = (unsigned*)(ws + 112 * MB);        // 256 KB
    unsigned*       rowptr  = (unsigned*)(ws + 113 * MB);        // 256 KB + 4
    unsigned*       cursor  = (unsigned*)(ws + 114 * MB);        // 256 KB
    unsigned*       bsum    = (unsigned*)(ws + 115 * MB);        // 1 KB
    unsigned*       csr     = (unsigned*)(ws + 116 * MB);        // 2 MB
    unsigned short* wbuf    = (unsigned short*)(ws + 118 * MB);  // 256 KB (7 tiles)

    const int edgeBlocks = (Bc * Ec) / 256;      // 2048
    const int scanBlocks = BN / 256;             // 256
    const int gemmBlocks = BN / 128;             // 512 (2 m-iters of 64 rows)

    // Weight prep (once per launch; builds LDS-image tiles)
    k_prep<<<7, 1024, 0, stream>>>(Wq, Wk, Wv, Wo, ff1, ff2, wbuf);

    // CSR build
    k_init<<<scanBlocks, 256, 0, stream>>>(counts);
    k_hist<<<edgeBlocks, 256, 0, stream>>>(eidx, ne, counts);
    k_scan1<<<scanBlocks, 256, 0, stream>>>(counts, rowptr, bsum);
    k_scan2<<<1, 256, 0, stream>>>(bsum);
    k_scan3<<<scanBlocks, 256, 0, stream>>>(rowptr, bsum, counts, cursor);
    k_fill<<<edgeBlocks, 256, 0, stream>>>(eidx, ne, cursor, csr);

    // Fused QKV (h read once; prepped tiles 0..2 through one LDS buffer)
    k_qkv3<<<gemmBlocks, 256, 0, stream>>>(h, wbuf, Q, Kp, V);

    // Attention (bf16 out)
    k_attn<<<BN / 4, 256, 0, stream>>>(Q, Kp, V, ef, eidx, rowptr, csr, We, attn);

    // Wo + bo + residual(h,f32) + LN1 -> h1 (bf16); tile 3
    k_gemm<128, 2, 2><<<dim3(gemmBlocks, 1), 256, 0, stream>>>(
        attn, wbuf + 3 * 16384, bo, h, ln1g, ln1b, h1, 128);

    // ff1 + b1 + relu -> mid (bf16); tiles 4,5 via blockIdx.y
    k_gemm<128, 1, 2><<<dim3(gemmBlocks, 2), 256, 0, stream>>>(
        h1, wbuf + 4 * 16384, b1, nullptr, nullptr, nullptr, mid, 256);

    // ff2 + b2 + residual(h1,bf16) + LN2 -> out (f32); tile 6
    k_gemm<256, 3, 2><<<dim3(gemmBlocks, 1), 256, 0, stream>>>(
        mid, wbuf + 6 * 16384, b2, h1, ln2g, ln2b, d_out, 128);
}

// Round 8
// 273.894 us; speedup vs baseline: 1.2282x; 1.1443x over previous
//
#include <hip/hip_runtime.h>
#include <string.h>

// Problem constants
constexpr int Bc   = 4;
constexpr int Nc   = 16384;
constexpr int Ec   = 131072;   // 2^17
constexpr int Hc   = 8;
constexpr int Dc   = 16;
constexpr int HIDc = 128;
constexpr int BN   = Bc * Nc;  // 65536
constexpr int CAP  = 64;       // bucket capacity; P(deg>64) ~ e^-35, never

// R7 post-mortem: non-attn phase stuck at ~260-280us across R4-R7 despite
// GEMM rewrites; traffic floor is ~60-120us. 12 dispatches + small kernels
// => dispatch/serialization overhead hypothesis. R8: 12 -> 5 dispatches:
// (1) CSR scan dropped -> fixed-cap buckets (atomic slot), zeroing folded
// into k_prep; (2) wo_ln+ff1+ff2_ln fused into k_mlp (h1 in regs, C->A
// layout transforms via per-wave padded LDS tiles), killing mid/h1 traffic.

typedef __bf16 bf16_t;
typedef bf16_t bf16x8 __attribute__((ext_vector_type(8)));
typedef float  f32x4  __attribute__((ext_vector_type(4)));

union BF8 { bf16x8 v; uint4 u; unsigned short s[8]; };

// ---------- helpers ----------
__device__ inline float b2f(unsigned short u) {
    return __uint_as_float(((unsigned)u) << 16);
}
__device__ inline unsigned short f2b(float f) {
    unsigned b = __float_as_uint(f);
    unsigned r = (b + 0x7FFFu + ((b >> 16) & 1u)) >> 16;  // RNE
    return (unsigned short)r;
}
__device__ inline float lo16(unsigned u) { return __uint_as_float(u << 16); }
__device__ inline float hi16(unsigned u) { return __uint_as_float(u & 0xFFFF0000u); }

// ---------- weight prep + counts zero ----------
// tiles: 0=Wq 1=Wk 2=Wv 3=Wo (KD=128), 4=ff1[:,0:128] 5=ff1[:,128:256],
//        6=ff2 (KD=256, 32768 shorts). Layout per tile:
//        wt[n*KD + (c^(n&7))*8 + j] = W[(c*8+j)*pitch + col0 + n]
__global__ __launch_bounds__(1024) void k_prep(const float* __restrict__ Wq,
                                               const float* __restrict__ Wk,
                                               const float* __restrict__ Wv,
                                               const float* __restrict__ Wo,
                                               const float* __restrict__ ff1,
                                               const float* __restrict__ ff2,
                                               unsigned short* __restrict__ wbuf,
                                               unsigned* __restrict__ counts) {
    if (blockIdx.x >= 7) {                     // zero bucket counts
        int i = (blockIdx.x - 7) * 1024 + threadIdx.x;
        counts[i] = 0u;
        return;
    }
    int t = blockIdx.x;
    const float* W;
    int pitch, col0, chunks;
    size_t off = (size_t)t * 16384;
    switch (t) {
        case 0: W = Wq;  pitch = 128; col0 = 0;   chunks = 16; break;
        case 1: W = Wk;  pitch = 128; col0 = 0;   chunks = 16; break;
        case 2: W = Wv;  pitch = 128; col0 = 0;   chunks = 16; break;
        case 3: W = Wo;  pitch = 128; col0 = 0;   chunks = 16; break;
        case 4: W = ff1; pitch = 256; col0 = 0;   chunks = 16; break;
        case 5: W = ff1; pitch = 256; col0 = 128; chunks = 16; break;
        default: W = ff2; pitch = 128; col0 = 0;  chunks = 32; break;
    }
    const int KD = chunks * 8;
    for (int idx = threadIdx.x; idx < 128 * chunks; idx += 1024) {
        int n = idx & 127;
        int c = idx >> 7;
        BF8 pk;
#pragma unroll
        for (int j = 0; j < 8; ++j)
            pk.v[j] = (bf16_t)W[(size_t)(c * 8 + j) * pitch + col0 + n];
        *(uint4*)&wbuf[off + (size_t)n * KD + (c ^ (n & 7)) * 8] = pk.u;
    }
}

// ---------- bucket CSR fill (no scan) ----------
__global__ __launch_bounds__(256) void k_fill2(const int* __restrict__ eidx,
                                               const int* __restrict__ nedges,
                                               unsigned* __restrict__ counts,
                                               unsigned* __restrict__ csr2) {
    int t = blockIdx.x * 256 + threadIdx.x;   // [0, B*E)
    int b = t >> 17;
    int e = t & (Ec - 1);
    if (e >= nedges[b]) return;
    int dst = eidx[(size_t)(b * 2 + 1) * Ec + e];
    unsigned node = (unsigned)(b * Nc + dst);
    unsigned slot = atomicAdd(&counts[node], 1u);
    if (slot < (unsigned)CAP) csr2[(size_t)node * CAP + slot] = (unsigned)e;
}

// ---------- fused QKV: A-fragments in regs, 3 prepped tiles via one LDS ----
__global__ __launch_bounds__(256) void k_qkv3(const float* __restrict__ h,
                                              const unsigned short* __restrict__ wbuf,
                                              unsigned short* __restrict__ Q,
                                              unsigned short* __restrict__ K,
                                              unsigned short* __restrict__ V) {
    __shared__ __attribute__((aligned(16))) unsigned short wt[16384]; // 32KB
    const int wave = threadIdx.x >> 6, lane = threadIdx.x & 63;
    const int nn = lane & 15, q = lane >> 4;

    bf16x8 afrag[2][4];
#pragma unroll
    for (int it = 0; it < 2; ++it) {
        const int arow = (blockIdx.x * 2 + it) * 64 + wave * 16 + nn;
        const float* A = h + (size_t)arow * 128;
#pragma unroll
        for (int ks = 0; ks < 4; ++ks) {
            int k0 = ks * 32 + q * 8;
            float4 f0 = *(const float4*)(A + k0);
            float4 f1 = *(const float4*)(A + k0 + 4);
            BF8 pk;
            pk.v[0] = (bf16_t)f0.x; pk.v[1] = (bf16_t)f0.y;
            pk.v[2] = (bf16_t)f0.z; pk.v[3] = (bf16_t)f0.w;
            pk.v[4] = (bf16_t)f1.x; pk.v[5] = (bf16_t)f1.y;
            pk.v[6] = (bf16_t)f1.z; pk.v[7] = (bf16_t)f1.w;
            afrag[it][ks] = pk.v;
        }
    }

#pragma unroll 1
    for (int s = 0; s < 3; ++s) {
        unsigned short* O = (s == 0) ? Q : ((s == 1) ? K : V);
        if (s) __syncthreads();
        {
            const uint4* src = (const uint4*)(wbuf + (size_t)s * 16384);
            uint4* dst = (uint4*)wt;
            for (int i = threadIdx.x; i < 2048; i += 256) dst[i] = src[i];
        }
        __syncthreads();
#pragma unroll 1
        for (int it = 0; it < 2; ++it) {
            const int row0 = (blockIdx.x * 2 + it) * 64 + wave * 16;
            f32x4 acc[8];
#pragma unroll
            for (int nt = 0; nt < 8; ++nt) acc[nt] = (f32x4){0.f, 0.f, 0.f, 0.f};
#pragma unroll
            for (int nt = 0; nt < 8; ++nt) {
                int n = nt * 16 + nn;
#pragma unroll
                for (int ks = 0; ks < 4; ++ks) {
                    int c = ks * 4 + q;
                    BF8 bf;
                    bf.u = *(const uint4*)&wt[n * 128 + (c ^ (n & 7)) * 8];
                    acc[nt] = __builtin_amdgcn_mfma_f32_16x16x32_bf16(
                        afrag[it][ks], bf.v, acc[nt], 0, 0, 0);
                }
            }
#pragma unroll
            for (int nt = 0; nt < 8; ++nt) {
                int col = nt * 16 + nn;
#pragma unroll
                for (int r = 0; r < 4; ++r)
                    O[(size_t)(row0 + q * 4 + r) * 128 + col] = f2b(acc[nt][r]);
            }
        }
    }
}

// ---------- attention: wave/node, online softmax, bucket CSR ----------
__global__ __launch_bounds__(256) void k_attn(const unsigned short* __restrict__ Q,
                                              const unsigned short* __restrict__ K,
                                              const unsigned short* __restrict__ V,
                                              const float* __restrict__ ef,
                                              const int* __restrict__ eidx,
                                              const unsigned* __restrict__ counts,
                                              const unsigned* __restrict__ csr2,
                                              const float* __restrict__ We,
                                              unsigned short* __restrict__ attn) {
    int wave = threadIdx.x >> 6, lane = threadIdx.x & 63;
    int i = blockIdx.x * 4 + wave;            // node id in [0, BN)
    int b = i >> 14;                          // N = 16384 = 2^14
    int hh = lane >> 3;
    int j  = lane & 7;
    int col = hh * 16 + j * 2;

    unsigned qv = *(const unsigned*)(Q + (size_t)i * 128 + col);
    float q0 = lo16(qv), q1 = hi16(qv);
    float we0 = We[hh], we1 = We[8 + hh];

    unsigned deg = counts[i];
    if (deg > (unsigned)CAP) deg = CAP;
    const unsigned* bkt = csr2 + (size_t)i * CAP;
    const int* srcArr = eidx + (size_t)(b * 2) * Ec;
    const unsigned short* Kb = K + (size_t)b * Nc * 128;
    const unsigned short* Vb = V + (size_t)b * Nc * 128;
    const float* efb = ef + (size_t)b * Ec * 2;

    float m = -INFINITY, l = 0.f, a0 = 0.f, a1 = 0.f;
    unsigned p = 0;
    for (; p + 4 <= deg; p += 4) {
        unsigned e4[4]; int s4[4]; unsigned kv[4], vv[4]; float2 f4[4];
#pragma unroll
        for (int u = 0; u < 4; ++u) e4[u] = bkt[p + u];
#pragma unroll
        for (int u = 0; u < 4; ++u) s4[u] = srcArr[e4[u]];
#pragma unroll
        for (int u = 0; u < 4; ++u) {
            kv[u] = *(const unsigned*)(Kb + (size_t)s4[u] * 128 + col);
            vv[u] = *(const unsigned*)(Vb + (size_t)s4[u] * 128 + col);
            f4[u] = *(const float2*)(efb + (size_t)e4[u] * 2);
        }
        float lg[4];
#pragma unroll
        for (int u = 0; u < 4; ++u) {
            float d = q0 * lo16(kv[u]) + q1 * hi16(kv[u]);
            d += __shfl_xor(d, 1, 64);
            d += __shfl_xor(d, 2, 64);
            d += __shfl_xor(d, 4, 64);
            lg[u] = 0.25f * d + f4[u].x * we0 + f4[u].y * we1;
        }
        float M = fmaxf(fmaxf(fmaxf(lg[0], lg[1]), fmaxf(lg[2], lg[3])), m);
        float sc = __expf(m - M);
        float pr[4];
#pragma unroll
        for (int u = 0; u < 4; ++u) pr[u] = __expf(lg[u] - M);
        l  = l * sc + ((pr[0] + pr[1]) + (pr[2] + pr[3]));
        a0 = a0 * sc + pr[0] * lo16(vv[0]) + pr[1] * lo16(vv[1])
                     + pr[2] * lo16(vv[2]) + pr[3] * lo16(vv[3]);
        a1 = a1 * sc + pr[0] * hi16(vv[0]) + pr[1] * hi16(vv[1])
                     + pr[2] * hi16(vv[2]) + pr[3] * hi16(vv[3]);
        m = M;
    }
    for (; p < deg; ++p) {
        int e = (int)bkt[p];
        int src = srcArr[e];
        unsigned kv = *(const unsigned*)(Kb + (size_t)src * 128 + col);
        unsigned vv = *(const unsigned*)(Vb + (size_t)src * 128 + col);
        float2 f2v = *(const float2*)(efb + (size_t)e * 2);
        float d = q0 * lo16(kv) + q1 * hi16(kv);
        d += __shfl_xor(d, 1, 64);
        d += __shfl_xor(d, 2, 64);
        d += __shfl_xor(d, 4, 64);
        float lg = 0.25f * d + f2v.x * we0 + f2v.y * we1;
        float nm = fmaxf(m, lg);
        float sc = __expf(m - nm);
        float pr = __expf(lg - nm);
        l  = l * sc + pr;
        a0 = a0 * sc + pr * lo16(vv);
        a1 = a1 * sc + pr * hi16(vv);
        m = nm;
    }
    float rcp = 1.f / fmaxf(l, 1e-6f);
    unsigned pack = (unsigned)f2b(a0 * rcp) | ((unsigned)f2b(a1 * rcp) << 16);
    *(unsigned*)(attn + (size_t)i * 128 + col) = pack;
}

// ---------- fused MLP: wo+LN1 -> ff1+relu -> ff2+LN2, one kernel ----------
// Per block: 64 rows (4 waves x 16). h1 kept in f32 registers for LN2 resid.
// C-layout -> A-layout via per-wave padded LDS tiles (pitches 16B-aligned).
constexpr int H1P  = 136;  // shorts/row, h1 tile (128 + 8 pad)
constexpr int MIDP = 264;  // shorts/row, mid tile (256 + 8 pad)

__global__ __launch_bounds__(256) void k_mlp(const unsigned short* __restrict__ attn,
                                             const float* __restrict__ h,
                                             const unsigned short* __restrict__ wbuf,
                                             const float* __restrict__ bo,
                                             const float* __restrict__ ln1g,
                                             const float* __restrict__ ln1b,
                                             const float* __restrict__ b1,
                                             const float* __restrict__ b2,
                                             const float* __restrict__ ln2g,
                                             const float* __restrict__ ln2b,
                                             float* __restrict__ out) {
    __shared__ __attribute__((aligned(16))) unsigned short wLDS[32768];       // 64KB
    __shared__ __attribute__((aligned(16))) unsigned short hT[4 * 16 * H1P];  // 17KB
    __shared__ __attribute__((aligned(16))) unsigned short midT[4 * 16 * MIDP]; // 33KB

    const int wave = threadIdx.x >> 6, lane = threadIdx.x & 63;
    const int nn = lane & 15, q = lane >> 4;
    const int rowbase = blockIdx.x * 64 + wave * 16;
    unsigned short* hTw   = hT   + wave * 16 * H1P;
    unsigned short* midTw = midT + wave * 16 * MIDP;

    // ---- stage Wo (tile 3) ----
    {
        const uint4* src = (const uint4*)(wbuf + 3 * 16384);
        uint4* dst = (uint4*)wLDS;
        for (int i = threadIdx.x; i < 2048; i += 256) dst[i] = src[i];
    }
    // ---- A-frags (attn, bf16) + resid h (f32), in flight during stage ----
    bf16x8 af0[4];
    {
        const unsigned short* A = attn + (size_t)(rowbase + nn) * 128;
#pragma unroll
        for (int ks = 0; ks < 4; ++ks) {
            BF8 pk;
            pk.u = *(const uint4*)(A + ks * 32 + q * 8);
            af0[ks] = pk.v;
        }
    }
    float res[8][4];
#pragma unroll
    for (int nt = 0; nt < 8; ++nt)
#pragma unroll
        for (int r = 0; r < 4; ++r)
            res[nt][r] = h[(size_t)(rowbase + q * 4 + r) * 128 + nt * 16 + nn];
    __syncthreads();

    // ---- Wo MFMA ----
    f32x4 acc[8];
#pragma unroll
    for (int nt = 0; nt < 8; ++nt) acc[nt] = (f32x4){0.f, 0.f, 0.f, 0.f};
#pragma unroll
    for (int nt = 0; nt < 8; ++nt) {
        int n = nt * 16 + nn;
#pragma unroll
        for (int ks = 0; ks < 4; ++ks) {
            int c = ks * 4 + q;
            BF8 bf;
            bf.u = *(const uint4*)&wLDS[n * 128 + (c ^ (n & 7)) * 8];
            acc[nt] = __builtin_amdgcn_mfma_f32_16x16x32_bf16(af0[ks], bf.v,
                                                              acc[nt], 0, 0, 0);
        }
    }

    // ---- + bo + resid -> LN1 -> h1 (f32 regs) ----
    float h1v[8][4];
    {
        float rs[4] = {0, 0, 0, 0}, rq[4] = {0, 0, 0, 0};
#pragma unroll
        for (int nt = 0; nt < 8; ++nt) {
            float bv = bo[nt * 16 + nn];
#pragma unroll
            for (int r = 0; r < 4; ++r) {
                float x = acc[nt][r] + bv + res[nt][r];
                h1v[nt][r] = x;
                rs[r] += x; rq[r] += x * x;
            }
        }
#pragma unroll
        for (int r = 0; r < 4; ++r) {
#pragma unroll
            for (int o = 1; o < 16; o <<= 1) {
                rs[r] += __shfl_xor(rs[r], o, 64);
                rq[r] += __shfl_xor(rq[r], o, 64);
            }
        }
#pragma unroll
        for (int r = 0; r < 4; ++r) {
            float mean = rs[r] * (1.f / 128.f);
            float var  = rq[r] * (1.f / 128.f) - mean * mean;
            float rstd = rsqrtf(var + 1e-5f);
#pragma unroll
            for (int nt = 0; nt < 8; ++nt) {
                int col = nt * 16 + nn;
                h1v[nt][r] = (h1v[nt][r] - mean) * rstd * ln1g[col] + ln1b[col];
            }
        }
    }
    // ---- write h1 bf16 to own LDS tile (C-layout scatter) ----
#pragma unroll
    for (int nt = 0; nt < 8; ++nt)
#pragma unroll
        for (int r = 0; r < 4; ++r)
            hTw[(q * 4 + r) * H1P + nt * 16 + nn] = f2b(h1v[nt][r]);

    __syncthreads();   // all waves done reading Wo from wLDS
    // ---- stage ff1 (tiles 4+5, 64KB) ----
    {
        const uint4* src = (const uint4*)(wbuf + 4 * 16384);
        uint4* dst = (uint4*)wLDS;
        for (int i = threadIdx.x; i < 4096; i += 256) dst[i] = src[i];
    }
    __syncthreads();

    // ---- ff1 A-frags from hTw (A-layout reads) ----
    bf16x8 af1[4];
#pragma unroll
    for (int ks = 0; ks < 4; ++ks) {
        BF8 pk;
        pk.u = *(const uint4*)&hTw[nn * H1P + ks * 32 + q * 8];
        af1[ks] = pk.v;
    }
    // ---- ff1 MFMA: N=256 -> 16 n-tiles ----
    f32x4 acc1[16];
#pragma unroll
    for (int nt = 0; nt < 16; ++nt) acc1[nt] = (f32x4){0.f, 0.f, 0.f, 0.f};
#pragma unroll
    for (int nt = 0; nt < 16; ++nt) {
        const unsigned short* wb = wLDS + (nt >> 3) * 16384 + ((nt & 7) * 16 + nn) * 128;
#pragma unroll
        for (int ks = 0; ks < 4; ++ks) {
            int c = ks * 4 + q;
            BF8 bf;
            bf.u = *(const uint4*)&wb[(c ^ (nn & 7)) * 8];
            acc1[nt] = __builtin_amdgcn_mfma_f32_16x16x32_bf16(af1[ks], bf.v,
                                                               acc1[nt], 0, 0, 0);
        }
    }
    // ---- + b1 + relu -> mid bf16 -> own LDS tile ----
#pragma unroll
    for (int nt = 0; nt < 16; ++nt) {
        int col = nt * 16 + nn;
        float bv = b1[col];
#pragma unroll
        for (int r = 0; r < 4; ++r)
            midTw[(q * 4 + r) * MIDP + col] = f2b(fmaxf(acc1[nt][r] + bv, 0.f));
    }

    __syncthreads();   // all waves done reading ff1 from wLDS
    // ---- stage ff2 (tile 6, 64KB) ----
    {
        const uint4* src = (const uint4*)(wbuf + 6 * 16384);
        uint4* dst = (uint4*)wLDS;
        for (int i = threadIdx.x; i < 4096; i += 256) dst[i] = src[i];
    }
    __syncthreads();

    // ---- ff2 A-frags from midTw (KD=256 -> 8 ks) ----
    bf16x8 af2[8];
#pragma unroll
    for (int ks = 0; ks < 8; ++ks) {
        BF8 pk;
        pk.u = *(const uint4*)&midTw[nn * MIDP + ks * 32 + q * 8];
        af2[ks] = pk.v;
    }
    // ---- ff2 MFMA ----
    f32x4 acc2[8];
#pragma unroll
    for (int nt = 0; nt < 8; ++nt) acc2[nt] = (f32x4){0.f, 0.f, 0.f, 0.f};
#pragma unroll
    for (int nt = 0; nt < 8; ++nt) {
        int n = nt * 16 + nn;
#pragma unroll
        for (int ks = 0; ks < 8; ++ks) {
            int c = ks * 4 + q;
            BF8 bf;
            bf.u = *(const uint4*)&wLDS[n * 256 + (c ^ (n & 7)) * 8];
            acc2[nt] = __builtin_amdgcn_mfma_f32_16x16x32_bf16(af2[ks], bf.v,
                                                               acc2[nt], 0, 0, 0);
        }
    }
    // ---- + b2 + h1 resid -> LN2 -> out f32 ----
    {
        float rs[4] = {0, 0, 0, 0}, rq[4] = {0, 0, 0, 0};
#pragma unroll
        for (int nt = 0; nt < 8; ++nt) {
            float bv = b2[nt * 16 + nn];
#pragma unroll
            for (int r = 0; r < 4; ++r) {
                float x = acc2[nt][r] + bv + h1v[nt][r];
                acc2[nt][r] = x;
                rs[r] += x; rq[r] += x * x;
            }
        }
#pragma unroll
        for (int r = 0; r < 4; ++r) {
#pragma unroll
            for (int o = 1; o < 16; o <<= 1) {
                rs[r] += __shfl_xor(rs[r], o, 64);
                rq[r] += __shfl_xor(rq[r], o, 64);
            }
        }
#pragma unroll
        for (int r = 0; r < 4; ++r) {
            float mean = rs[r] * (1.f / 128.f);
            float var  = rq[r] * (1.f / 128.f) - mean * mean;
            float rstd = rsqrtf(var + 1e-5f);
            int row = rowbase + q * 4 + r;
#pragma unroll
            for (int nt = 0; nt < 8; ++nt) {
                int col = nt * 16 + nn;
                out[(size_t)row * 128 + col] =
                    (acc2[nt][r] - mean) * rstd * ln2g[col] + ln2b[col];
            }
        }
    }
}

extern "C" void kernel_launch(void* const* d_in, const int* in_sizes, int n_in,
                              void* d_out, int out_size, void* d_ws, size_t ws_size,
                              hipStream_t stream) {
    const float* h    = (const float*)d_in[0];
    const float* ef   = (const float*)d_in[1];
    const int*   eidx = (const int*)d_in[2];
    const int*   ne   = (const int*)d_in[3];
    const float* Wq   = (const float*)d_in[4];
    const float* Wk   = (const float*)d_in[5];
    const float* Wv   = (const float*)d_in[6];
    const float* Wo   = (const float*)d_in[7];
    const float* bo   = (const float*)d_in[8];
    const float* We   = (const float*)d_in[9];
    const float* ln1g = (const float*)d_in[10];
    const float* ln1b = (const float*)d_in[11];
    const float* ln2g = (const float*)d_in[12];
    const float* ln2b = (const float*)d_in[13];
    const float* ff1  = (const float*)d_in[14];
    const float* b1   = (const float*)d_in[15];
    const float* ff2  = (const float*)d_in[16];
    const float* b2   = (const float*)d_in[17];

    constexpr size_t MB = 1024 * 1024;
    char* ws = (char*)d_ws;
    unsigned short* Q      = (unsigned short*)(ws + 0 * MB);    // 16 MB bf16
    unsigned short* Kp     = (unsigned short*)(ws + 16 * MB);   // 16 MB bf16
    unsigned short* V      = (unsigned short*)(ws + 32 * MB);   // 16 MB bf16
    unsigned short* attn   = (unsigned short*)(ws + 48 * MB);   // 16 MB bf16
    unsigned*       counts = (unsigned*)(ws + 64 * MB);         // 256 KB
    unsigned short* wbuf   = (unsigned short*)(ws + 65 * MB);   // 224 KB (7 tiles)
    unsigned*       csr2   = (unsigned*)(ws + 66 * MB);         // 16 MB (CAP=64)

    const int edgeBlocks = (Bc * Ec) / 256;      // 2048
    const int qkvBlocks  = BN / 128;             // 512
    const int mlpBlocks  = BN / 64;              // 1024

    // 1. weight prep (blocks 0-6) + counts zero (blocks 7-70)
    k_prep<<<71, 1024, 0, stream>>>(Wq, Wk, Wv, Wo, ff1, ff2, wbuf, counts);
    // 2. bucket CSR fill
    k_fill2<<<edgeBlocks, 256, 0, stream>>>(eidx, ne, counts, csr2);
    // 3. fused QKV
    k_qkv3<<<qkvBlocks, 256, 0, stream>>>(h, wbuf, Q, Kp, V);
    // 4. attention
    k_attn<<<BN / 4, 256, 0, stream>>>(Q, Kp, V, ef, eidx, counts, csr2, We, attn);
    // 5. fused MLP (wo+LN1 -> ff1+relu -> ff2+LN2)
    k_mlp<<<mlpBlocks, 256, 0, stream>>>(attn, h, wbuf, bo, ln1g, ln1b,
                                         b1, b2, ln2g, ln2b, (float*)d_out);
}